// Round 1
// baseline (313.238 us; speedup 1.0000x reference)
//
#include <hip/hip_runtime.h>

typedef unsigned short u16;
typedef __attribute__((ext_vector_type(8))) short bf16x8;
typedef __attribute__((ext_vector_type(4))) float f32x4;

#define Bb 2
#define Tt 2048
#define Dd 1024
#define Hh 16
#define HD 64
#define NTOK (Bb*Tt)   // 4096

__device__ __forceinline__ u16 f2b(float f) {
    unsigned u = __float_as_uint(f);
    unsigned r = (u + 0x7fffu + ((u >> 16) & 1u)) >> 16;
    return (u16)r;
}

// ---------------- fp32 -> bf16 convert ----------------
__global__ void cvt_f32_bf16(const float* __restrict__ in, u16* __restrict__ out, int n4) {
    int i = blockIdx.x * blockDim.x + threadIdx.x;
    if (i < n4) {
        float4 f = ((const float4*)in)[i];
        ushort4 o;
        o.x = f2b(f.x); o.y = f2b(f.y); o.z = f2b(f.z); o.w = f2b(f.w);
        ((ushort4*)out)[i] = o;
    }
}

// ---------------- NT GEMM: C[m][n] = sum_k A[m][k]*Bt[n][k] + bias[n] ----------------
// MODE 0: scatter bf16 into Q(b,h,t,hd), K(b,h,t,hd), Vt(b,h,hd,t)   (N=3072)
// MODE 1: fp32 out[m*N+n]
#define LDP 40   // padded LDS row stride (bf16 elems): 80B -> 2-way bank aliasing (free)

template<int MODE>
__global__ __launch_bounds__(256, 2)
void gemm_bt(const u16* __restrict__ A, const u16* __restrict__ Bt,
             const float* __restrict__ bias, int M, int N, int K,
             u16* __restrict__ Qo, u16* __restrict__ Ko, u16* __restrict__ Vo,
             float* __restrict__ Co) {
    __shared__ alignas(16) u16 As[128 * LDP];
    __shared__ alignas(16) u16 Bs[128 * LDP];
    const int tid = threadIdx.x;
    const int wave = tid >> 6, lane = tid & 63;
    const int quad = lane >> 4, l16 = lane & 15;
    const int wm = (wave & 1) * 64, wn = (wave >> 1) * 64;
    const int m0 = blockIdx.x * 128, n0 = blockIdx.y * 128;

    f32x4 acc[4][4];
    for (int i = 0; i < 4; ++i)
        for (int j = 0; j < 4; ++j)
            acc[i][j] = (f32x4){0.f, 0.f, 0.f, 0.f};

    for (int k0 = 0; k0 < K; k0 += 32) {
        // stage A tile: 128 rows x 32 cols, 512 chunks of 8 bf16
        for (int c = tid; c < 512; c += 256) {
            int row = c >> 2, cc = (c & 3) << 3;
            *(uint4*)(&As[row * LDP + cc]) = *(const uint4*)(A + (size_t)(m0 + row) * K + k0 + cc);
        }
        for (int c = tid; c < 512; c += 256) {
            int row = c >> 2, cc = (c & 3) << 3;
            *(uint4*)(&Bs[row * LDP + cc]) = *(const uint4*)(Bt + (size_t)(n0 + row) * K + k0 + cc);
        }
        __syncthreads();
        bf16x8 a[4], b[4];
        for (int i = 0; i < 4; ++i)
            a[i] = *(const bf16x8*)(&As[(wm + i * 16 + l16) * LDP + quad * 8]);
        for (int i = 0; i < 4; ++i)
            b[i] = *(const bf16x8*)(&Bs[(wn + i * 16 + l16) * LDP + quad * 8]);
        for (int i = 0; i < 4; ++i)
            for (int j = 0; j < 4; ++j)
                acc[i][j] = __builtin_amdgcn_mfma_f32_16x16x32_bf16(a[i], b[j], acc[i][j], 0, 0, 0);
        __syncthreads();
    }

    // epilogue
    for (int i = 0; i < 4; ++i) {
        for (int j = 0; j < 4; ++j) {
            for (int r = 0; r < 4; ++r) {
                int m = m0 + wm + i * 16 + quad * 4 + r;
                int n = n0 + wn + j * 16 + l16;
                float v = acc[i][j][r] + bias[n];
                if (MODE == 0) {
                    u16 bv = f2b(v);
                    int bidx = m >> 11, t = m & 2047;
                    int s = n >> 10, c = n & 1023;
                    int hh = c >> 6, d = c & 63;
                    size_t base = (size_t)(bidx * Hh + hh);
                    if (s == 0)      Qo[(base * Tt + t) * HD + d] = bv;
                    else if (s == 1) Ko[(base * Tt + t) * HD + d] = bv;
                    else             Vo[(base * HD + d) * Tt + t] = bv;
                } else {
                    Co[(size_t)m * N + n] = v;
                }
            }
        }
    }
}

// ---------------- flash attention (causal), bf16 MFMA ----------------
// grid: (T/64, B*H); block 256 = 4 waves, each wave owns 16 q-rows.
#define LKP 72   // padded LDS stride for 64-wide tiles

__global__ __launch_bounds__(256, 2)
void attn_fwd(const u16* __restrict__ Q, const u16* __restrict__ Kb,
              const u16* __restrict__ Vt, u16* __restrict__ Ao) {
    const int qt = blockIdx.x, bh = blockIdx.y;
    const int q0 = qt * 64;
    const u16* Qp = Q + (size_t)bh * Tt * HD;
    const u16* Kp = Kb + (size_t)bh * Tt * HD;
    const u16* Vp = Vt + (size_t)bh * HD * Tt;
    const int tid = threadIdx.x;
    const int wave = tid >> 6, lane = tid & 63;
    const int quad = lane >> 4, l16 = lane & 15;

    __shared__ alignas(16) u16 Ks[64 * LKP];
    __shared__ alignas(16) u16 Vs[64 * LKP];
    __shared__ alignas(16) u16 Ps[4][16 * LKP];

    // Q fragments for this wave's 16 rows (A-operand layout), direct from global
    bf16x8 aq[2];
    {
        int qrow = q0 + wave * 16 + l16;
        for (int kk = 0; kk < 2; ++kk)
            aq[kk] = *(const bf16x8*)(Qp + (size_t)qrow * HD + kk * 32 + quad * 8);
    }

    f32x4 o[4];
    for (int nt = 0; nt < 4; ++nt) o[nt] = (f32x4){0.f, 0.f, 0.f, 0.f};
    float mrow[4], lrow[4];
    for (int r = 0; r < 4; ++r) { mrow[r] = -3e38f; lrow[r] = 0.f; }

    for (int kt = 0; kt <= qt; ++kt) {
        const int k0 = kt * 64;
        // stage K (t,hd) and Vt (hd,t) tiles
        for (int c = tid; c < 512; c += 256) {
            int row = c >> 3, cc = (c & 7) << 3;
            *(uint4*)(&Ks[row * LKP + cc]) = *(const uint4*)(Kp + (size_t)(k0 + row) * HD + cc);
        }
        for (int c = tid; c < 512; c += 256) {
            int row = c >> 3, cc = (c & 7) << 3;
            *(uint4*)(&Vs[row * LKP + cc]) = *(const uint4*)(Vp + (size_t)row * Tt + k0 + cc);
        }
        __syncthreads();

        // scores: S stripe 16 x 64 per wave
        f32x4 s[4];
        for (int nt = 0; nt < 4; ++nt) {
            f32x4 z = (f32x4){0.f, 0.f, 0.f, 0.f};
            for (int kk = 0; kk < 2; ++kk) {
                bf16x8 bk = *(const bf16x8*)(&Ks[(nt * 16 + l16) * LKP + kk * 32 + quad * 8]);
                z = __builtin_amdgcn_mfma_f32_16x16x32_bf16(aq[kk], bk, z, 0, 0, 0);
            }
            s[nt] = z;
        }
        // scale + causal mask
        for (int nt = 0; nt < 4; ++nt) {
            int col = k0 + nt * 16 + l16;
            for (int r = 0; r < 4; ++r) {
                int row = q0 + wave * 16 + quad * 4 + r;
                float v = s[nt][r] * 0.125f;
                s[nt][r] = (col <= row) ? v : -3e38f;
            }
        }
        // online softmax: row max across 16 lanes (cols) per reg
        float alpha[4];
        for (int r = 0; r < 4; ++r) {
            float v = fmaxf(fmaxf(s[0][r], s[1][r]), fmaxf(s[2][r], s[3][r]));
            for (int off = 1; off < 16; off <<= 1) v = fmaxf(v, __shfl_xor(v, off, 64));
            float mn = fmaxf(mrow[r], v);
            alpha[r] = __expf(mrow[r] - mn);
            mrow[r] = mn;
        }
        for (int nt = 0; nt < 4; ++nt)
            for (int r = 0; r < 4; ++r)
                s[nt][r] = __expf(s[nt][r] - mrow[r]);
        for (int r = 0; r < 4; ++r) {
            float v = s[0][r] + s[1][r] + s[2][r] + s[3][r];
            for (int off = 1; off < 16; off <<= 1) v += __shfl_xor(v, off, 64);
            lrow[r] = lrow[r] * alpha[r] + v;
            for (int nt = 0; nt < 4; ++nt) o[nt][r] *= alpha[r];
        }
        // P: C-layout regs -> LDS -> A-operand fragments (per-wave private stripe)
        u16* Pw = &Ps[wave][0];
        for (int nt = 0; nt < 4; ++nt)
            for (int r = 0; r < 4; ++r)
                Pw[(quad * 4 + r) * LKP + nt * 16 + l16] = f2b(s[nt][r]);
        // PV
        for (int kk = 0; kk < 2; ++kk) {
            bf16x8 ap = *(const bf16x8*)(&Pw[l16 * LKP + kk * 32 + quad * 8]);
            for (int nt = 0; nt < 4; ++nt) {
                bf16x8 bv = *(const bf16x8*)(&Vs[(nt * 16 + l16) * LKP + kk * 32 + quad * 8]);
                o[nt] = __builtin_amdgcn_mfma_f32_16x16x32_bf16(ap, bv, o[nt], 0, 0, 0);
            }
        }
        __syncthreads();
    }

    // epilogue: attn[b*T + t][h*64 + d] bf16
    const int hh = bh & (Hh - 1), bidx = bh >> 4;
    for (int nt = 0; nt < 4; ++nt) {
        for (int r = 0; r < 4; ++r) {
            int row = q0 + wave * 16 + quad * 4 + r;
            int col = hh * HD + nt * 16 + l16;
            float v = o[nt][r] / lrow[r];
            Ao[((size_t)bidx * Tt + row) * Dd + col] = f2b(v);
        }
    }
}

extern "C" void kernel_launch(void* const* d_in, const int* in_sizes, int n_in,
                              void* d_out, int out_size, void* d_ws, size_t ws_size,
                              hipStream_t stream) {
    const float* x      = (const float*)d_in[0];
    const float* W_qkv  = (const float*)d_in[1];
    const float* b_qkv  = (const float*)d_in[2];
    const float* W_proj = (const float*)d_in[3];
    const float* b_proj = (const float*)d_in[4];
    float* out = (float*)d_out;

    char* ws = (char*)d_ws;
    u16* xb     = (u16*)(ws);
    u16* Wqkvb  = (u16*)(ws + (8u << 20));
    u16* Wprojb = (u16*)(ws + (14u << 20));
    u16* Qb     = (u16*)(ws + (16u << 20));
    u16* Kb     = (u16*)(ws + (24u << 20));
    u16* Vtb    = (u16*)(ws + (32u << 20));
    u16* attnb  = (u16*)(ws + (40u << 20));

    // converts
    cvt_f32_bf16<<<(NTOK * Dd / 4) / 256, 256, 0, stream>>>(x, xb, NTOK * Dd / 4);
    cvt_f32_bf16<<<(3 * Dd * Dd / 4) / 256, 256, 0, stream>>>(W_qkv, Wqkvb, 3 * Dd * Dd / 4);
    cvt_f32_bf16<<<(Dd * Dd / 4) / 256, 256, 0, stream>>>(W_proj, Wprojb, Dd * Dd / 4);

    // QKV projection: (4096 x 3072 x 1024)
    {
        dim3 grid(NTOK / 128, (3 * Dd) / 128);
        gemm_bt<0><<<grid, 256, 0, stream>>>(xb, Wqkvb, b_qkv, NTOK, 3 * Dd, Dd,
                                             Qb, Kb, Vtb, nullptr);
    }
    // attention
    {
        dim3 grid(Tt / 64, Bb * Hh);
        attn_fwd<<<grid, 256, 0, stream>>>(Qb, Kb, Vtb, attnb);
    }
    // output projection: (4096 x 1024 x 1024) -> fp32 + bias
    {
        dim3 grid(NTOK / 128, Dd / 128);
        gemm_bt<1><<<grid, 256, 0, stream>>>(attnb, Wprojb, b_proj, NTOK, Dd, Dd,
                                             nullptr, nullptr, nullptr, out);
    }
}

// Round 2
// 265.040 us; speedup vs baseline: 1.1819x; 1.1819x over previous
//
#include <hip/hip_runtime.h>

typedef unsigned short u16;
typedef __attribute__((ext_vector_type(8))) short bf16x8;
typedef __attribute__((ext_vector_type(4))) float f32x4;

#define Bb 2
#define Tt 2048
#define Dd 1024
#define Hh 16
#define HD 64
#define NTOK (Bb*Tt)   // 4096

__device__ __forceinline__ u16 f2b(float f) {
    unsigned u = __float_as_uint(f);
    unsigned r = (u + 0x7fffu + ((u >> 16) & 1u)) >> 16;
    return (u16)r;
}

// ---------------- fp32 -> bf16 convert ----------------
__global__ void cvt_f32_bf16(const float* __restrict__ in, u16* __restrict__ out, int n4) {
    int i = blockIdx.x * blockDim.x + threadIdx.x;
    if (i < n4) {
        float4 f = ((const float4*)in)[i];
        ushort4 o;
        o.x = f2b(f.x); o.y = f2b(f.y); o.z = f2b(f.z); o.w = f2b(f.w);
        ((ushort4*)out)[i] = o;
    }
}

// ---------------- NT GEMM: C[m][n] = sum_k A[m][k]*Bt[n][k] + bias[n] ----------------
// MODE 0: scatter bf16 into Q(b,h,t,hd), K(b,h,t,hd), Vt(b,h,hd,t)   (N=3072)
// MODE 1: fp32 out[m*N+n]
#define LDP 40   // padded LDS row stride (bf16 elems): 80B -> 2-way bank aliasing (free)

template<int MODE>
__global__ __launch_bounds__(256, 2)
void gemm_bt(const u16* __restrict__ A, const u16* __restrict__ Bt,
             const float* __restrict__ bias, int M, int N, int K,
             u16* __restrict__ Qo, u16* __restrict__ Ko, u16* __restrict__ Vo,
             float* __restrict__ Co) {
    __shared__ alignas(16) u16 As[128 * LDP];
    __shared__ alignas(16) u16 Bs[128 * LDP];
    const int tid = threadIdx.x;
    const int wave = tid >> 6, lane = tid & 63;
    const int quad = lane >> 4, l16 = lane & 15;
    const int wm = (wave & 1) * 64, wn = (wave >> 1) * 64;
    const int m0 = blockIdx.x * 128, n0 = blockIdx.y * 128;

    f32x4 acc[4][4];
    for (int i = 0; i < 4; ++i)
        for (int j = 0; j < 4; ++j)
            acc[i][j] = (f32x4){0.f, 0.f, 0.f, 0.f};

    for (int k0 = 0; k0 < K; k0 += 32) {
        for (int c = tid; c < 512; c += 256) {
            int row = c >> 2, cc = (c & 3) << 3;
            *(uint4*)(&As[row * LDP + cc]) = *(const uint4*)(A + (size_t)(m0 + row) * K + k0 + cc);
        }
        for (int c = tid; c < 512; c += 256) {
            int row = c >> 2, cc = (c & 3) << 3;
            *(uint4*)(&Bs[row * LDP + cc]) = *(const uint4*)(Bt + (size_t)(n0 + row) * K + k0 + cc);
        }
        __syncthreads();
        bf16x8 a[4], b[4];
        for (int i = 0; i < 4; ++i)
            a[i] = *(const bf16x8*)(&As[(wm + i * 16 + l16) * LDP + quad * 8]);
        for (int i = 0; i < 4; ++i)
            b[i] = *(const bf16x8*)(&Bs[(wn + i * 16 + l16) * LDP + quad * 8]);
        for (int i = 0; i < 4; ++i)
            for (int j = 0; j < 4; ++j)
                acc[i][j] = __builtin_amdgcn_mfma_f32_16x16x32_bf16(a[i], b[j], acc[i][j], 0, 0, 0);
        __syncthreads();
    }

    for (int i = 0; i < 4; ++i) {
        for (int j = 0; j < 4; ++j) {
            for (int r = 0; r < 4; ++r) {
                int m = m0 + wm + i * 16 + quad * 4 + r;
                int n = n0 + wn + j * 16 + l16;
                float v = acc[i][j][r] + bias[n];
                if (MODE == 0) {
                    u16 bv = f2b(v);
                    int bidx = m >> 11, t = m & 2047;
                    int s = n >> 10, c = n & 1023;
                    int hh = c >> 6, d = c & 63;
                    size_t base = (size_t)(bidx * Hh + hh);
                    if (s == 0)      Qo[(base * Tt + t) * HD + d] = bv;
                    else if (s == 1) Ko[(base * Tt + t) * HD + d] = bv;
                    else             Vo[(base * HD + d) * Tt + t] = bv;
                } else {
                    Co[(size_t)m * N + n] = v;
                }
            }
        }
    }
}

// ---------------- flash attention (causal), bf16 MFMA, TRANSPOSED form ----------------
// S^T = K * Q^T, O^T = V^T * P^T. Softmax reduction is in-lane (16 regs) + 2 quad
// shuffles; m/l/alpha per-lane. grid: (T/64 heavy-first, B*H); block 256 = 4 waves.
#define LKP 72   // padded LDS stride (bf16): 144B = 36 dwords -> 2-way alias (free)

__global__ __launch_bounds__(256, 4)
void attn_fwd(const u16* __restrict__ Q, const u16* __restrict__ Kb,
              const u16* __restrict__ Vt, u16* __restrict__ Ao) {
    const int qt = (int)gridDim.x - 1 - (int)blockIdx.x;  // heavy blocks first
    const int bh = blockIdx.y;
    const int q0 = qt * 64;
    const u16* Qp = Q + (size_t)bh * Tt * HD;
    const u16* Kp = Kb + (size_t)bh * Tt * HD;
    const u16* Vp = Vt + (size_t)bh * HD * Tt;
    const int tid = threadIdx.x;
    const int wave = tid >> 6, lane = tid & 63;
    const int quad = lane >> 4, l16 = lane & 15;

    __shared__ alignas(16) u16 Ks[64 * LKP];
    __shared__ alignas(16) u16 Vs[64 * LKP];
    __shared__ alignas(16) u16 Ps[4][16 * LKP];

    // staging mapping: each thread handles rows {row, row+32} at col..col+7
    const int srow = tid >> 3, scol = (tid & 7) << 3;

    // Q fragments (B-operand: lane l16 = q-row), direct from global
    const int qrow_g = q0 + wave * 16 + l16;
    bf16x8 aq[2];
    for (int kk = 0; kk < 2; ++kk)
        aq[kk] = *(const bf16x8*)(Qp + (size_t)qrow_g * HD + kk * 32 + quad * 8);

    f32x4 o[4];
    for (int nt = 0; nt < 4; ++nt) o[nt] = (f32x4){0.f, 0.f, 0.f, 0.f};
    float m_q = -3e38f, l_q = 0.f;

    // prefetch tile 0
    uint4 kreg0, kreg1, vreg0, vreg1;
    {
        kreg0 = *(const uint4*)(Kp + (size_t)srow * HD + scol);
        kreg1 = *(const uint4*)(Kp + (size_t)(srow + 32) * HD + scol);
        vreg0 = *(const uint4*)(Vp + (size_t)srow * Tt + scol);
        vreg1 = *(const uint4*)(Vp + (size_t)(srow + 32) * Tt + scol);
    }

    for (int kt = 0; kt <= qt; ++kt) {
        const int k0 = kt * 64;
        // write prefetched tile to LDS
        *(uint4*)(&Ks[srow * LKP + scol]) = kreg0;
        *(uint4*)(&Ks[(srow + 32) * LKP + scol]) = kreg1;
        *(uint4*)(&Vs[srow * LKP + scol]) = vreg0;
        *(uint4*)(&Vs[(srow + 32) * LKP + scol]) = vreg1;
        __syncthreads();
        // prefetch next tile (latency overlapped with compute below)
        if (kt < qt) {
            const int kn = k0 + 64;
            kreg0 = *(const uint4*)(Kp + (size_t)(kn + srow) * HD + scol);
            kreg1 = *(const uint4*)(Kp + (size_t)(kn + srow + 32) * HD + scol);
            vreg0 = *(const uint4*)(Vp + (size_t)srow * Tt + kn + scol);
            vreg1 = *(const uint4*)(Vp + (size_t)(srow + 32) * Tt + kn + scol);
        }

        // S^T stripe: 64 keys x 16 q per wave. lane holds key=nt*16+quad*4+r, q=l16
        f32x4 s[4];
        for (int nt = 0; nt < 4; ++nt) {
            f32x4 z = (f32x4){0.f, 0.f, 0.f, 0.f};
            for (int kk = 0; kk < 2; ++kk) {
                bf16x8 ak = *(const bf16x8*)(&Ks[(nt * 16 + l16) * LKP + kk * 32 + quad * 8]);
                z = __builtin_amdgcn_mfma_f32_16x16x32_bf16(ak, aq[kk], z, 0, 0, 0);
            }
            s[nt] = z;
        }
        // scale + causal mask (key <= qrow)
        for (int nt = 0; nt < 4; ++nt) {
            for (int r = 0; r < 4; ++r) {
                int key = k0 + nt * 16 + quad * 4 + r;
                float v = s[nt][r] * 0.125f;
                s[nt][r] = (key <= qrow_g) ? v : -3e38f;
            }
        }
        // online softmax: in-lane over 16 regs, then 2 cross-quad shuffles
        float vm = s[0][0];
        for (int nt = 0; nt < 4; ++nt)
            for (int r = 0; r < 4; ++r) vm = fmaxf(vm, s[nt][r]);
        vm = fmaxf(vm, __shfl_xor(vm, 16, 64));
        vm = fmaxf(vm, __shfl_xor(vm, 32, 64));
        float mn = fmaxf(m_q, vm);
        float alpha = __expf(m_q - mn);
        m_q = mn;
        float vs = 0.f;
        for (int nt = 0; nt < 4; ++nt)
            for (int r = 0; r < 4; ++r) {
                s[nt][r] = __expf(s[nt][r] - mn);
                vs += s[nt][r];
            }
        vs += __shfl_xor(vs, 16, 64);
        vs += __shfl_xor(vs, 32, 64);
        l_q = l_q * alpha + vs;
        for (int nt = 0; nt < 4; ++nt)
            for (int r = 0; r < 4; ++r) o[nt][r] *= alpha;

        // P^T -> LDS (wave-private stripe, layout [q][k]): 4 packed b64 stores
        u16* Pw = &Ps[wave][0];
        for (int nt = 0; nt < 4; ++nt) {
            ushort4 p4;
            p4.x = f2b(s[nt][0]); p4.y = f2b(s[nt][1]);
            p4.z = f2b(s[nt][2]); p4.w = f2b(s[nt][3]);
            *(ushort4*)(&Pw[l16 * LKP + nt * 16 + quad * 4]) = p4;
        }
        // O^T += V^T * P^T
        for (int kk = 0; kk < 2; ++kk) {
            bf16x8 bp = *(const bf16x8*)(&Pw[l16 * LKP + kk * 32 + quad * 8]);
            for (int nt = 0; nt < 4; ++nt) {
                bf16x8 av = *(const bf16x8*)(&Vs[(nt * 16 + l16) * LKP + kk * 32 + quad * 8]);
                o[nt] = __builtin_amdgcn_mfma_f32_16x16x32_bf16(av, bp, o[nt], 0, 0, 0);
            }
        }
        __syncthreads();
    }

    // epilogue: lane owns q=l16 row; 4 consecutive hd per nt -> packed b64 stores
    const int hh = bh & (Hh - 1), bidx = bh >> 4;
    const float rinv = 1.0f / l_q;
    u16* orow = Ao + ((size_t)bidx * Tt + qrow_g) * Dd + hh * HD;
    for (int nt = 0; nt < 4; ++nt) {
        ushort4 p4;
        p4.x = f2b(o[nt][0] * rinv); p4.y = f2b(o[nt][1] * rinv);
        p4.z = f2b(o[nt][2] * rinv); p4.w = f2b(o[nt][3] * rinv);
        *(ushort4*)(orow + nt * 16 + quad * 4) = p4;
    }
}

extern "C" void kernel_launch(void* const* d_in, const int* in_sizes, int n_in,
                              void* d_out, int out_size, void* d_ws, size_t ws_size,
                              hipStream_t stream) {
    const float* x      = (const float*)d_in[0];
    const float* W_qkv  = (const float*)d_in[1];
    const float* b_qkv  = (const float*)d_in[2];
    const float* W_proj = (const float*)d_in[3];
    const float* b_proj = (const float*)d_in[4];
    float* out = (float*)d_out;

    char* ws = (char*)d_ws;
    u16* xb     = (u16*)(ws);
    u16* Wqkvb  = (u16*)(ws + (8u << 20));
    u16* Wprojb = (u16*)(ws + (14u << 20));
    u16* Qb     = (u16*)(ws + (16u << 20));
    u16* Kb     = (u16*)(ws + (24u << 20));
    u16* Vtb    = (u16*)(ws + (32u << 20));
    u16* attnb  = (u16*)(ws + (40u << 20));

    cvt_f32_bf16<<<(NTOK * Dd / 4) / 256, 256, 0, stream>>>(x, xb, NTOK * Dd / 4);
    cvt_f32_bf16<<<(3 * Dd * Dd / 4) / 256, 256, 0, stream>>>(W_qkv, Wqkvb, 3 * Dd * Dd / 4);
    cvt_f32_bf16<<<(Dd * Dd / 4) / 256, 256, 0, stream>>>(W_proj, Wprojb, Dd * Dd / 4);

    {
        dim3 grid(NTOK / 128, (3 * Dd) / 128);
        gemm_bt<0><<<grid, 256, 0, stream>>>(xb, Wqkvb, b_qkv, NTOK, 3 * Dd, Dd,
                                             Qb, Kb, Vtb, nullptr);
    }
    {
        dim3 grid(Tt / 64, Bb * Hh);
        attn_fwd<<<grid, 256, 0, stream>>>(Qb, Kb, Vtb, attnb);
    }
    {
        dim3 grid(NTOK / 128, Dd / 128);
        gemm_bt<1><<<grid, 256, 0, stream>>>(attnb, Wprojb, b_proj, NTOK, Dd, Dd,
                                             nullptr, nullptr, nullptr, out);
    }
}

// Round 3
// 255.642 us; speedup vs baseline: 1.2253x; 1.0368x over previous
//
#include <hip/hip_runtime.h>

typedef unsigned short u16;
typedef __attribute__((ext_vector_type(8))) short bf16x8;
typedef __attribute__((ext_vector_type(4))) float f32x4;

#define Bb 2
#define Tt 2048
#define Dd 1024
#define Hh 16
#define HD 64
#define NTOK (Bb*Tt)   // 4096

__device__ __forceinline__ u16 f2b(float f) {
    unsigned u = __float_as_uint(f);
    unsigned r = (u + 0x7fffu + ((u >> 16) & 1u)) >> 16;
    return (u16)r;
}

// async global->LDS, 16B per lane; LDS dest = wave-uniform base + lane*16
__device__ __forceinline__ void g2l16(const u16* g, u16* l) {
    __builtin_amdgcn_global_load_lds(
        (const __attribute__((address_space(1))) unsigned int*)g,
        (__attribute__((address_space(3))) unsigned int*)l,
        16, 0, 0);
}

// ---------------- fused fp32 -> bf16 convert (x, W_qkv, W_proj in one launch) ----------------
#define N4X  (NTOK * Dd / 4)        // 1048576
#define N4WQ (3 * Dd * Dd / 4)      // 786432
#define N4WP (Dd * Dd / 4)          // 262144
__global__ void cvt_all(const float* __restrict__ x, const float* __restrict__ wq,
                        const float* __restrict__ wp, u16* __restrict__ xb,
                        u16* __restrict__ wqb, u16* __restrict__ wpb) {
    int i = blockIdx.x * blockDim.x + threadIdx.x;
    const float* src; u16* dst; int j;
    if (i < N4X)                { src = x;  dst = xb;  j = i; }
    else if (i < N4X + N4WQ)    { src = wq; dst = wqb; j = i - N4X; }
    else                        { src = wp; dst = wpb; j = i - N4X - N4WQ; }
    float4 f = ((const float4*)src)[j];
    ushort4 o;
    o.x = f2b(f.x); o.y = f2b(f.y); o.z = f2b(f.z); o.w = f2b(f.w);
    ((ushort4*)dst)[j] = o;
}

// ---------------- NT GEMM: C[m][n] = sum_k A[m][k]*Bt[n][k] + bias[n] ----------------
// m97 structure: global_load_lds width-16 staging, no-pad LDS (BK=32).
// MODE 0: scatter bf16 into Q(b,h,t,hd), K(b,h,t,hd), V(b,h,t,hd)   (N=3072)
// MODE 1: fp32 out[m*N+n]
template<int MODE>
__global__ __launch_bounds__(256, 2)
void gemm_bt(const u16* __restrict__ A, const u16* __restrict__ Bt,
             const float* __restrict__ bias, int M, int N, int K,
             u16* __restrict__ Qo, u16* __restrict__ Ko, u16* __restrict__ Vo,
             float* __restrict__ Co) {
    __shared__ alignas(16) u16 As[128 * 32];
    __shared__ alignas(16) u16 Bs[128 * 32];
    const int tid = threadIdx.x;
    const int wave = tid >> 6, lane = tid & 63;
    const int quad = lane >> 4, l16 = lane & 15;
    const int wm = (wave & 1) * 64, wn = (wave >> 1) * 64;
    const int m0 = blockIdx.x * 128, n0 = blockIdx.y * 128;
    const int lrow = lane >> 2, lcol = (lane & 3) << 3;

    f32x4 acc[4][4];
    for (int i = 0; i < 4; ++i)
        for (int j = 0; j < 4; ++j)
            acc[i][j] = (f32x4){0.f, 0.f, 0.f, 0.f};

    for (int k0 = 0; k0 < K; k0 += 32) {
        for (int c = 0; c < 2; ++c) {
            const int rb = (c * 4 + wave) * 16;
            g2l16(A  + (size_t)(m0 + rb + lrow) * K + k0 + lcol, &As[rb * 32 + (lane << 3)]);
            g2l16(Bt + (size_t)(n0 + rb + lrow) * K + k0 + lcol, &Bs[rb * 32 + (lane << 3)]);
        }
        __syncthreads();
        bf16x8 a[4], b[4];
        for (int i = 0; i < 4; ++i)
            a[i] = *(const bf16x8*)(&As[(wm + i * 16 + l16) * 32 + quad * 8]);
        for (int i = 0; i < 4; ++i)
            b[i] = *(const bf16x8*)(&Bs[(wn + i * 16 + l16) * 32 + quad * 8]);
        for (int i = 0; i < 4; ++i)
            for (int j = 0; j < 4; ++j)
                acc[i][j] = __builtin_amdgcn_mfma_f32_16x16x32_bf16(a[i], b[j], acc[i][j], 0, 0, 0);
        __syncthreads();
    }

    for (int i = 0; i < 4; ++i) {
        for (int j = 0; j < 4; ++j) {
            for (int r = 0; r < 4; ++r) {
                int m = m0 + wm + i * 16 + quad * 4 + r;
                int n = n0 + wn + j * 16 + l16;
                float v = acc[i][j][r] + bias[n];
                if (MODE == 0) {
                    u16 bv = f2b(v);
                    int bidx = m >> 11, t = m & 2047;
                    int s = n >> 10, c = n & 1023;
                    int hh = c >> 6, d = c & 63;
                    size_t base = (size_t)(bidx * Hh + hh);
                    u16* dst = (s == 0) ? Qo : (s == 1) ? Ko : Vo;
                    dst[(base * Tt + t) * HD + d] = bv;
                } else {
                    Co[(size_t)m * N + n] = v;
                }
            }
        }
    }
}

// ---------------- V (b,h,t,hd) -> Vt (b,h,hd,t) via LDS transpose ----------------
__global__ __launch_bounds__(256)
void transpose_v(const u16* __restrict__ V, u16* __restrict__ Vt) {
    __shared__ u16 Ls[64 * 66];
    const int t0 = blockIdx.x * 64, bh = blockIdx.y;
    const int tid = threadIdx.x;
    const int r = tid >> 2, c = (tid & 3) << 4;
    const u16* src = V + ((size_t)bh * Tt + t0 + r) * HD + c;
    *(uint4*)(&Ls[r * 66 + c]) = *(const uint4*)src;
    *(uint4*)(&Ls[r * 66 + c + 8]) = *(const uint4*)(src + 8);
    __syncthreads();
    const int d = tid >> 2, tc = (tid & 3) << 4;
    u16 tmp[16];
    for (int j = 0; j < 16; ++j) tmp[j] = Ls[(tc + j) * 66 + d];
    u16* dst = Vt + ((size_t)bh * HD + d) * Tt + t0 + tc;
    *(uint4*)(dst)     = *(const uint4*)(tmp);
    *(uint4*)(dst + 8) = *(const uint4*)(tmp + 8);
}

// ---------------- flash attention (causal), bf16 MFMA, transposed, 128-key tiles ----------------
// S^T = K * Q^T, O^T = V^T * P^T. Paired q-tiles {31-pair, pair}: 17 iters/block uniform.
// LDS strides chosen = 2 mod 32 dwords -> b128 reads 2-way aliased (free).
#define KSP 68    // Ks row stride (64 hd + 4)
#define VSP 132   // Vs/Ps row stride (128 keys + 4)

__global__ __launch_bounds__(256, 2)
void attn_fwd(const u16* __restrict__ Q, const u16* __restrict__ Kg,
              const u16* __restrict__ Vt, u16* __restrict__ Ao) {
    const int pair = blockIdx.x, bh = blockIdx.y;
    const u16* Qp = Q + (size_t)bh * Tt * HD;
    const u16* Kp = Kg + (size_t)bh * Tt * HD;
    const u16* Vp = Vt + (size_t)bh * HD * Tt;
    const int tid = threadIdx.x;
    const int wave = tid >> 6, lane = tid & 63;
    const int quad = lane >> 4, l16 = lane & 15;
    const int hh = bh & (Hh - 1), bidx = bh >> 4;

    __shared__ alignas(16) u16 Ks[128 * KSP];
    __shared__ alignas(16) u16 Vs[64 * VSP];
    __shared__ alignas(16) u16 Ps[4][16 * VSP];

    // staging: K 128 rows x 64 cols (4 steps of 32 rows); V 64 rows x 128 cols (4 steps of 16 rows)
    const int srK = tid >> 3, scK = (tid & 7) << 3;
    const int srV = tid >> 4, scV = (tid & 15) << 3;

    for (int half = 0; half < 2; ++half) {
        const int qt = half ? pair : (31 - pair);   // heavy tile first
        const int q0 = qt * 64;
        const int qrow_g = q0 + wave * 16 + l16;
        bf16x8 aq[2];
        for (int kk = 0; kk < 2; ++kk)
            aq[kk] = *(const bf16x8*)(Qp + (size_t)qrow_g * HD + kk * 32 + quad * 8);

        f32x4 o[4];
        for (int nt = 0; nt < 4; ++nt) o[nt] = (f32x4){0.f, 0.f, 0.f, 0.f};
        float m_q = -3e38f, l_q = 0.f;
        const int nit = (qt + 2) >> 1;   // ceil((qt+1)/2)

        uint4 kpre[4], vpre[4];
        for (int r = 0; r < 4; ++r) {
            kpre[r] = *(const uint4*)(Kp + (size_t)(srK + r * 32) * HD + scK);
            vpre[r] = *(const uint4*)(Vp + (size_t)(srV + r * 16) * Tt + scV);
        }

        for (int kt = 0; kt < nit; ++kt) {
            const int k0 = kt * 128;
            for (int r = 0; r < 4; ++r) {
                *(uint4*)(&Ks[(srK + r * 32) * KSP + scK]) = kpre[r];
                *(uint4*)(&Vs[(srV + r * 16) * VSP + scV]) = vpre[r];
            }
            __syncthreads();
            if (kt + 1 < nit) {
                const int kn = k0 + 128;
                for (int r = 0; r < 4; ++r) {
                    kpre[r] = *(const uint4*)(Kp + (size_t)(kn + srK + r * 32) * HD + scK);
                    vpre[r] = *(const uint4*)(Vp + (size_t)(srV + r * 16) * Tt + kn + scV);
                }
            }

            // S^T: 128 keys x 16 q per wave
            f32x4 s[8];
            for (int nt = 0; nt < 8; ++nt) {
                f32x4 z = (f32x4){0.f, 0.f, 0.f, 0.f};
                for (int kk = 0; kk < 2; ++kk) {
                    bf16x8 ak = *(const bf16x8*)(&Ks[(nt * 16 + l16) * KSP + kk * 32 + quad * 8]);
                    z = __builtin_amdgcn_mfma_f32_16x16x32_bf16(ak, aq[kk], z, 0, 0, 0);
                }
                s[nt] = z;
            }
            // scale (log2e folded) + causal mask
            const float sc = 0.125f * 1.44269504f;
            for (int nt = 0; nt < 8; ++nt)
                for (int r = 0; r < 4; ++r) {
                    int key = k0 + nt * 16 + quad * 4 + r;
                    float v = s[nt][r] * sc;
                    s[nt][r] = (key <= qrow_g) ? v : -3e38f;
                }
            // online softmax (base-2): in-lane over 32 regs + 2 cross-quad shuffles
            float vm = -3e38f;
            for (int nt = 0; nt < 8; ++nt)
                for (int r = 0; r < 4; ++r) vm = fmaxf(vm, s[nt][r]);
            vm = fmaxf(vm, __shfl_xor(vm, 16, 64));
            vm = fmaxf(vm, __shfl_xor(vm, 32, 64));
            float mn = fmaxf(m_q, vm);
            float alpha = exp2f(m_q - mn);
            m_q = mn;
            float vs = 0.f;
            for (int nt = 0; nt < 8; ++nt)
                for (int r = 0; r < 4; ++r) {
                    s[nt][r] = exp2f(s[nt][r] - mn);
                    vs += s[nt][r];
                }
            vs += __shfl_xor(vs, 16, 64);
            vs += __shfl_xor(vs, 32, 64);
            l_q = l_q * alpha + vs;
            for (int nt = 0; nt < 4; ++nt)
                for (int r = 0; r < 4; ++r) o[nt][r] *= alpha;

            // P^T -> LDS (wave-private), packed b64 stores; layout [q][128 k]
            u16* Pw = &Ps[wave][0];
            for (int nt = 0; nt < 8; ++nt) {
                ushort4 p4;
                p4.x = f2b(s[nt][0]); p4.y = f2b(s[nt][1]);
                p4.z = f2b(s[nt][2]); p4.w = f2b(s[nt][3]);
                *(ushort4*)(&Pw[l16 * VSP + nt * 16 + quad * 4]) = p4;
            }
            // O^T += V^T * P^T over both 64-key halves
            for (int h = 0; h < 2; ++h)
                for (int kk = 0; kk < 2; ++kk) {
                    bf16x8 bp = *(const bf16x8*)(&Pw[l16 * VSP + h * 64 + kk * 32 + quad * 8]);
                    for (int nt = 0; nt < 4; ++nt) {
                        bf16x8 av = *(const bf16x8*)(&Vs[(nt * 16 + l16) * VSP + h * 64 + kk * 32 + quad * 8]);
                        o[nt] = __builtin_amdgcn_mfma_f32_16x16x32_bf16(av, bp, o[nt], 0, 0, 0);
                    }
                }
            __syncthreads();
        }

        // epilogue
        const float rinv = 1.0f / l_q;
        u16* orow = Ao + ((size_t)bidx * Tt + qrow_g) * Dd + hh * HD;
        for (int nt = 0; nt < 4; ++nt) {
            ushort4 p4;
            p4.x = f2b(o[nt][0] * rinv); p4.y = f2b(o[nt][1] * rinv);
            p4.z = f2b(o[nt][2] * rinv); p4.w = f2b(o[nt][3] * rinv);
            *(ushort4*)(orow + nt * 16 + quad * 4) = p4;
        }
    }
}

extern "C" void kernel_launch(void* const* d_in, const int* in_sizes, int n_in,
                              void* d_out, int out_size, void* d_ws, size_t ws_size,
                              hipStream_t stream) {
    const float* x      = (const float*)d_in[0];
    const float* W_qkv  = (const float*)d_in[1];
    const float* b_qkv  = (const float*)d_in[2];
    const float* W_proj = (const float*)d_in[3];
    const float* b_proj = (const float*)d_in[4];
    float* out = (float*)d_out;

    char* ws = (char*)d_ws;
    u16* xb     = (u16*)(ws);               // 8 MB; reused as Vtb after GEMM1
    u16* Wqkvb  = (u16*)(ws + (8u << 20));
    u16* Wprojb = (u16*)(ws + (14u << 20));
    u16* Qb     = (u16*)(ws + (16u << 20));
    u16* Kb     = (u16*)(ws + (24u << 20));
    u16* Vb     = (u16*)(ws + (32u << 20));
    u16* attnb  = (u16*)(ws + (40u << 20));
    u16* Vtb    = xb;                        // alias: xb dead after GEMM1

    cvt_all<<<(N4X + N4WQ + N4WP) / 256, 256, 0, stream>>>(x, W_qkv, W_proj, xb, Wqkvb, Wprojb);

    {
        dim3 grid(NTOK / 128, (3 * Dd) / 128);
        gemm_bt<0><<<grid, 256, 0, stream>>>(xb, Wqkvb, b_qkv, NTOK, 3 * Dd, Dd,
                                             Qb, Kb, Vb, nullptr);
    }
    {
        dim3 grid(Tt / 64, Bb * Hh);
        transpose_v<<<grid, 256, 0, stream>>>(Vb, Vtb);
    }
    {
        dim3 grid(Tt / 128, Bb * Hh);   // 16 pairs x 32 bh
        attn_fwd<<<grid, 256, 0, stream>>>(Qb, Kb, Vtb, attnb);
    }
    {
        dim3 grid(NTOK / 128, Dd / 128);
        gemm_bt<1><<<grid, 256, 0, stream>>>(attnb, Wprojb, b_proj, NTOK, Dd, Dd,
                                             nullptr, nullptr, nullptr, out);
    }
}